// Round 2
// baseline (4784.782 us; speedup 1.0000x reference)
//
#include <hip/hip_runtime.h>
#include <hip/hip_bf16.h>
#include <math.h>

// Problem constants (fixed by reference)
#define B_    64
#define CIN   32
#define COUT  64
#define N_    512
#define T_    24
#define CC    288           // 3*(CIN+COUT)
#define FOUT  256           // 4*COUT
#define G_BSTRIDE   (CC*N_)    // 147456 floats per batch in g
#define FEA_BSTRIDE (FOUT*N_)  // 131072 floats per batch in fea
#define LAPSZ (N_*N_)          // 262144

// ---------------- unified tiled fp32 GEMM ----------------
// C[z] = A @ B[z] (+bias per-row | lap2 epilogue 2*acc - I)
// BM=128 fixed, 256 threads, TM=8. Template on BN (128 or 64).
#define BM  128
#define BKK 16
#define LDA_S 132   // padded leading dim for As (conflict-free transposed stores)

template <int BN_T, int TN_T>
__global__ __launch_bounds__(256, 2)
void gemm_main(const float* __restrict__ A, int arow,
               const float* __restrict__ Bm, int brow, int bz,
               float* __restrict__ C, int crow, int cz,
               const float* __restrict__ bias, int K, int mode)
{
    constexpr int LDB = BN_T + 4;
    __shared__ float As[2][BKK][LDA_S];
    __shared__ float Bs[2][BKK][LDB];

    const int tid = threadIdx.x;
    const int tx  = tid & 15;
    const int ty  = tid >> 4;
    const int m0  = blockIdx.y * BM;
    const int n0  = blockIdx.x * BN_T;
    const int z   = blockIdx.z;

    Bm += z * bz;
    C  += z * cz;

    // A-tile: 128 rows x 16 k; 512 float4 slots -> 2 per thread
    const int ar0 = tid >> 2;          // 0..63
    const int ar1 = ar0 + 64;          // 64..127
    const int ak  = (tid & 3) << 2;    // 0,4,8,12

    // B-tile: 16 x BN
    int bk0, bn_;
    if constexpr (BN_T == 128) { bk0 = tid >> 5; bn_ = (tid & 31) << 2; }
    else                       { bk0 = tid >> 4; bn_ = (tid & 15) << 2; }

    const float* Ap0 = A + (m0 + ar0) * arow + ak;
    const float* Ap1 = A + (m0 + ar1) * arow + ak;
    const float* Bp0 = Bm + bk0 * brow + n0 + bn_;

    float4 a0 = *(const float4*)Ap0;
    float4 a1 = *(const float4*)Ap1;
    float4 b0 = *(const float4*)Bp0;
    float4 b1;
    if constexpr (BN_T == 128) b1 = *(const float4*)(Bp0 + 8 * brow);

    float acc[8][TN_T];
#pragma unroll
    for (int i = 0; i < 8; ++i)
#pragma unroll
        for (int j = 0; j < TN_T; ++j) acc[i][j] = 0.f;

    const int NT = K / BKK;
    for (int kt = 0; kt < NT; ++kt) {
        const int p = kt & 1;
        // stage regs -> LDS (As transposed [k][m], padded; Bs natural [k][n])
        As[p][ak + 0][ar0] = a0.x; As[p][ak + 1][ar0] = a0.y;
        As[p][ak + 2][ar0] = a0.z; As[p][ak + 3][ar0] = a0.w;
        As[p][ak + 0][ar1] = a1.x; As[p][ak + 1][ar1] = a1.y;
        As[p][ak + 2][ar1] = a1.z; As[p][ak + 3][ar1] = a1.w;
        *(float4*)&Bs[p][bk0][bn_] = b0;
        if constexpr (BN_T == 128) *(float4*)&Bs[p][bk0 + 8][bn_] = b1;
        __syncthreads();
        // prefetch next K-tile into regs (overlaps compute)
        if (kt + 1 < NT) {
            const int ko = (kt + 1) * BKK;
            a0 = *(const float4*)(Ap0 + ko);
            a1 = *(const float4*)(Ap1 + ko);
            b0 = *(const float4*)(Bp0 + ko * brow);
            if constexpr (BN_T == 128) b1 = *(const float4*)(Bp0 + (ko + 8) * brow);
        }
#pragma unroll
        for (int k = 0; k < BKK; ++k) {
            const float4 av0 = *(const float4*)&As[p][k][ty * 8];
            const float4 av1 = *(const float4*)&As[p][k][ty * 8 + 4];
            const float am[8] = {av0.x, av0.y, av0.z, av0.w, av1.x, av1.y, av1.z, av1.w};
            float bb[TN_T];
            {
                const float4 bv0 = *(const float4*)&Bs[p][k][tx * TN_T];
                bb[0] = bv0.x; bb[1] = bv0.y; bb[2] = bv0.z; bb[3] = bv0.w;
                if constexpr (TN_T == 8) {
                    const float4 bv1 = *(const float4*)&Bs[p][k][tx * TN_T + 4];
                    bb[4] = bv1.x; bb[5] = bv1.y; bb[6] = bv1.z; bb[7] = bv1.w;
                }
            }
#pragma unroll
            for (int i = 0; i < 8; ++i)
#pragma unroll
                for (int j = 0; j < TN_T; ++j)
                    acc[i][j] = fmaf(am[i], bb[j], acc[i][j]);
        }
    }

    // epilogue
#pragma unroll
    for (int i = 0; i < 8; ++i) {
        const int gm = m0 + ty * 8 + i;
        const float add = (mode == 1) ? bias[gm] : 0.f;
        float* Cp = C + gm * crow + n0 + tx * TN_T;
#pragma unroll
        for (int jj = 0; jj < TN_T; jj += 4) {
            float4 v;
            if (mode == 2) {   // lap2: 2*acc - I
                const int gn = n0 + tx * TN_T + jj;
                v.x = 2.f * acc[i][jj + 0] - ((gm == gn + 0) ? 1.f : 0.f);
                v.y = 2.f * acc[i][jj + 1] - ((gm == gn + 1) ? 1.f : 0.f);
                v.z = 2.f * acc[i][jj + 2] - ((gm == gn + 2) ? 1.f : 0.f);
                v.w = 2.f * acc[i][jj + 3] - ((gm == gn + 3) ? 1.f : 0.f);
            } else {
                v.x = acc[i][jj + 0] + add; v.y = acc[i][jj + 1] + add;
                v.z = acc[i][jj + 2] + add; v.w = acc[i][jj + 3] + add;
            }
            *(float4*)(Cp + jj) = v;
        }
    }
}

// ---------------- small kernels ----------------
__global__ void transpose_lap_k(const float* __restrict__ sup, float* __restrict__ lap)
{
    const int idx = blockIdx.x * 256 + threadIdx.x;   // 262144
    const int nn = idx >> 9, q = idx & 511;
    lap[idx] = sup[q * N_ + nn];                      // lap1 = supports^T
}

__global__ void init_state_k(float* __restrict__ cbuf, float* __restrict__ g)
{
    const int idx = blockIdx.x * 256 + threadIdx.x;   // B*COUT*N = 2097152
    cbuf[idx] = 0.f;
    const int b = idx >> 15, u = (idx >> 9) & 63, q = idx & 511;
    g[b * G_BSTRIDE + (CIN + u) * 3 * N_ + q] = 0.f;  // h-slots (k=0) zero
}

__global__ void build_gx_k(const float* __restrict__ x, float* __restrict__ g, int t)
{
    const int idx = blockIdx.x * 256 + threadIdx.x;   // B*CIN*N = 1048576
    const int b = idx >> 14, c = (idx >> 9) & 31, q = idx & 511;
    g[b * G_BSTRIDE + c * 3 * N_ + q] = x[((((b << 5) + c) << 9) + q) * T_ + t];
}

__device__ __forceinline__ float sigf(float v) { return 1.f / (1.f + expf(-v)); }

__global__ void gates_k(const float* __restrict__ fea, float* __restrict__ cbuf,
                        float* __restrict__ g, float* __restrict__ hdst,
                        int t, int direct)
{
    const int idx = blockIdx.x * 256 + threadIdx.x;   // 2097152
    const int b = idx >> 15, u = (idx >> 9) & 63, q = idx & 511;
    const float* fb = fea + b * FEA_BSTRIDE;
    const int uq = u * N_ + q;
    const float gi = fb[uq];
    const float gj = fb[COUT * N_ + uq];
    const float gf = fb[2 * COUT * N_ + uq];
    const float go = fb[3 * COUT * N_ + uq];
    const float c  = cbuf[idx];
    const float nc = c * sigf(gf) + sigf(gi) * tanhf(gj);
    const float nh = tanhf(nc) * sigf(go);
    cbuf[idx] = nc;
    g[b * G_BSTRIDE + (CIN + u) * 3 * N_ + q] = nh;   // feed next step's k=0 h-slot
    if (direct) hdst[idx * T_ + t] = nh;              // out[b][u][q][t] (fallback)
    else        hdst[t * (B_ * COUT * N_) + idx] = nh;  // hseq[t][b][u][q]
}

__global__ void write_out_k(const float* __restrict__ hseq, float* __restrict__ out)
{
    __shared__ float tile[T_][N_ + 1];
    const int bu = blockIdx.x;                        // 4096 blocks = (b,u)
    const int tid = threadIdx.x;
    for (int i = tid; i < T_ * N_; i += 256) {
        const int t = i >> 9, q = i & 511;
        tile[t][q] = hseq[t * (B_ * COUT * N_) + bu * N_ + q];
    }
    __syncthreads();
    float* ob = out + bu * (N_ * T_);
    for (int i = tid; i < N_ * T_; i += 256) {
        const int q = i / T_;
        const int t = i - q * T_;
        ob[i] = tile[t][q];                           // out[..][q][t]
    }
}

// ---------------- launcher ----------------
extern "C" void kernel_launch(void* const* d_in, const int* in_sizes, int n_in,
                              void* d_out, int out_size, void* d_ws, size_t ws_size,
                              hipStream_t stream)
{
    const float* x    = (const float*)d_in[0];  // [64,32,512,24]
    const float* sup  = (const float*)d_in[1];  // [512,512]
    const float* W    = (const float*)d_in[2];  // [256,288]
    const float* bias = (const float*)d_in[3];  // [256]
    float* out = (float*)d_out;                 // [64,64,512,24]

    float* lap  = (float*)d_ws;                      // 2*262144
    float* g    = lap  + 2 * LAPSZ;                  // 64*288*512
    float* fea  = g    + B_ * G_BSTRIDE;             // 64*256*512
    float* cbuf = fea  + B_ * FEA_BSTRIDE;           // 64*64*512
    float* hseq = cbuf + B_ * COUT * N_;             // 24*64*64*512

    const size_t need_full =
        (size_t)(2 * LAPSZ + B_ * G_BSTRIDE + B_ * FEA_BSTRIDE + B_ * COUT * N_ +
                 (size_t)T_ * B_ * COUT * N_) * sizeof(float);   // ~283 MB
    const int direct = (ws_size < need_full) ? 1 : 0;  // fallback: strided out writes

    // Lap1 = supports^T ; Lap2 = 2*Lap1@Lap1 - I
    transpose_lap_k<<<LAPSZ / 256, 256, 0, stream>>>(sup, lap);
    gemm_main<128, 8><<<dim3(4, 4, 1), 256, 0, stream>>>(
        lap, N_, lap, N_, 0, lap + LAPSZ, N_, 0, nullptr, N_, 2);
    init_state_k<<<8192, 256, 0, stream>>>(cbuf, g);

    for (int t = 0; t < T_; ++t) {
        build_gx_k<<<4096, 256, 0, stream>>>(x, g, t);
        // spatial: g[b][c*3+1+z][:] = g[b][c*3][:] @ lap_z   (M=6144,N=512,K=512, z=2)
        gemm_main<64, 4><<<dim3(8, 48, 2), 256, 0, stream>>>(
            g, 3 * N_, lap, N_, LAPSZ, g + N_, 3 * N_, N_, nullptr, N_, 0);
        // fea[b] = W @ g[b] + bias   (M=256,N=512,K=288, z=b)
        gemm_main<128, 8><<<dim3(4, 2, B_), 256, 0, stream>>>(
            W, CC, g, N_, G_BSTRIDE, fea, N_, FEA_BSTRIDE, bias, CC, 1);
        gates_k<<<8192, 256, 0, stream>>>(fea, cbuf, g, direct ? out : hseq, t, direct);
    }
    if (!direct) write_out_k<<<4096, 256, 0, stream>>>(hseq, out);
}

// Round 6
// 2951.015 us; speedup vs baseline: 1.6214x; 1.6214x over previous
//
#include <hip/hip_runtime.h>
#include <math.h>

#define B_    64
#define N_    512
#define T_    24

typedef unsigned short u16;
using f32x4  = __attribute__((ext_vector_type(4))) float;
using bf16x8 = __attribute__((ext_vector_type(8))) short;

__device__ __forceinline__ u16 f2bf(float f){
    unsigned u = __float_as_uint(f);
    u += 0x7fffu + ((u >> 16) & 1u);          // RTN-even
    return (u16)(u >> 16);
}
__device__ __forceinline__ float bf2f(u16 s){
    return __uint_as_float(((unsigned)s) << 16);
}
__device__ __forceinline__ void glds16(const u16* gp, u16* lp){
    __builtin_amdgcn_global_load_lds(
        (const __attribute__((address_space(1))) unsigned int*)gp,
        (__attribute__((address_space(3))) unsigned int*)lp, 16, 0, 0);
}
__device__ __forceinline__ float sigf(float v){ return 1.f / (1.f + __expf(-v)); }
__device__ __forceinline__ float tanhfast(float v){ return 2.f / (1.f + __expf(-2.f*v)) - 1.f; }

// ===================== unified split-bf16 MFMA GEMM =====================
// C = (Ah+Al)(Bh+Bl) approx; A[row][k] k-contig, B supplied TRANSPOSED: Bt[col][k] k-contig.
// LDS layout per tile: [row][8 chunks of 8 bf16], chunk slot XOR-swizzled with (row&7).
// EPI=1: GEMM1 -> write hi/lo transposed into gT (c3' = 96*(z+1)+c).  EPI=2: GEMM2 -> feaT + bias.
template<int MT, int NT, int AROW, int BROW, int NKIT, int EPI>
__global__ __launch_bounds__(256, 2)
void mfma_gemm(const u16* __restrict__ Agh, const u16* __restrict__ Agl,
               const u16* __restrict__ Bgh, const u16* __restrict__ Bgl,
               int bz,
               u16* __restrict__ gTh, u16* __restrict__ gTl,
               float* __restrict__ feaT, const float* __restrict__ bias)
{
    constexpr int BM = MT*32, BN = NT*32;
    constexpr int NIA = BM/8, NIB = BN/8;           // global_load_lds instrs per part
    __shared__ __attribute__((aligned(16))) u16 Ah[BM*64];
    __shared__ __attribute__((aligned(16))) u16 Al[BM*64];
    __shared__ __attribute__((aligned(16))) u16 Bh[BN*64];
    __shared__ __attribute__((aligned(16))) u16 Bl[BN*64];

    const int tid  = threadIdx.x;
    const int lane = tid & 63, wave = tid >> 6;
    const int r16  = lane & 15, g = lane >> 4;
    const int wm = wave >> 1, wn = wave & 1;
    const int wtm0 = wm * (MT*16), wtn0 = wn * (NT*16);
    const int M0 = blockIdx.y * BM, N0 = blockIdx.x * BN;
    const int z  = blockIdx.z;

    // per-lane staging element-offsets at k=0 (source pre-swizzled: chunk gl holds gsrc = gl^(m&7))
    unsigned offA[NIA/4], offB[NIB/4];
#pragma unroll
    for (int ii = 0; ii < NIA/4; ii++){
        int c = (wave + ii*4)*64 + lane;
        int m = c >> 3, gl = c & 7, gs = gl ^ (m & 7);
        offA[ii] = (unsigned)((M0 + m)*AROW + gs*8);
    }
#pragma unroll
    for (int ii = 0; ii < NIB/4; ii++){
        int c = (wave + ii*4)*64 + lane;
        int m = c >> 3, gl = c & 7, gs = gl ^ (m & 7);
        offB[ii] = (unsigned)(z*bz + (N0 + m)*BROW + gs*8);
    }

    f32x4 acc[MT][NT];
#pragma unroll
    for (int i = 0; i < MT; i++)
#pragma unroll
        for (int j = 0; j < NT; j++) acc[i][j] = (f32x4){0.f, 0.f, 0.f, 0.f};

#pragma unroll 1
    for (int kt = 0; kt < NKIT; kt++){
        const unsigned ko = kt * 64u;
#pragma unroll
        for (int ii = 0; ii < NIA/4; ii++){
            glds16(Agh + offA[ii] + ko, &Ah[(wave + ii*4)*512]);
            glds16(Agl + offA[ii] + ko, &Al[(wave + ii*4)*512]);
        }
#pragma unroll
        for (int ii = 0; ii < NIB/4; ii++){
            glds16(Bgh + offB[ii] + ko, &Bh[(wave + ii*4)*512]);
            glds16(Bgl + offB[ii] + ko, &Bl[(wave + ii*4)*512]);
        }
        __syncthreads();
#pragma unroll
        for (int s = 0; s < 2; s++){
            bf16x8 fah[MT], fal[MT], fbh[NT], fbl[NT];
#pragma unroll
            for (int im = 0; im < MT; im++){
                const int row = wtm0 + im*16 + r16;
                const int e = row*64 + ((((s<<2)|g) ^ (row & 7)))*8;
                fah[im] = *(const bf16x8*)&Ah[e];
                fal[im] = *(const bf16x8*)&Al[e];
            }
#pragma unroll
            for (int in = 0; in < NT; in++){
                const int row = wtn0 + in*16 + r16;
                const int e = row*64 + ((((s<<2)|g) ^ (row & 7)))*8;
                fbh[in] = *(const bf16x8*)&Bh[e];
                fbl[in] = *(const bf16x8*)&Bl[e];
            }
#pragma unroll
            for (int im = 0; im < MT; im++)
#pragma unroll
                for (int in = 0; in < NT; in++){
                    acc[im][in] = __builtin_amdgcn_mfma_f32_16x16x32_bf16(fah[im], fbh[in], acc[im][in], 0, 0, 0);
                    acc[im][in] = __builtin_amdgcn_mfma_f32_16x16x32_bf16(fah[im], fbl[in], acc[im][in], 0, 0, 0);
                    acc[im][in] = __builtin_amdgcn_mfma_f32_16x16x32_bf16(fal[im], fbh[in], acc[im][in], 0, 0, 0);
                }
        }
        __syncthreads();
    }

    // epilogue: D element r of acc tile -> (row = wtm0+im*16+g*4+r, col = r16-based)  [m89-verified]
#pragma unroll
    for (int im = 0; im < MT; im++){
        const int mr = M0 + wtm0 + im*16 + g*4;     // 4 consecutive output rows
#pragma unroll
        for (int in = 0; in < NT; in++){
            const int q = N0 + wtn0 + in*16 + r16;
            const f32x4 v = acc[im][in];
            if constexpr (EPI == 1){
                const int c = mr - M0;              // channel within batch (BM==96)
                const size_t off = ((size_t)(blockIdx.y*512 + q))*320 + 96*(z + 1) + c;
                float vv[4] = {v.x, v.y, v.z, v.w};
                u16 hh[4], hl[4];
#pragma unroll
                for (int r = 0; r < 4; r++){ hh[r] = f2bf(vv[r]); hl[r] = f2bf(vv[r] - bf2f(hh[r])); }
                *(ushort4*)&gTh[off] = make_ushort4(hh[0], hh[1], hh[2], hh[3]);
                *(ushort4*)&gTl[off] = make_ushort4(hl[0], hl[1], hl[2], hl[3]);
            } else {
                const float4 bv = *(const float4*)&bias[mr];
                float4 o = make_float4(v.x + bv.x, v.y + bv.y, v.z + bv.z, v.w + bv.w);
                *(float4*)&feaT[((size_t)(z*512 + q))*256 + mr] = o;
            }
        }
    }
}

// ===================== setup kernels =====================
__global__ void transpose_x_k(const float* __restrict__ x, float* __restrict__ xF)
{
    const int tid = blockIdx.x*256 + threadIdx.x;   // 1048576 = (b,c,q)
    float xv[24];
    const float4* xp = (const float4*)(x + (size_t)tid*24);
#pragma unroll
    for (int j = 0; j < 6; j++) *(float4*)&xv[j*4] = xp[j];
#pragma unroll
    for (int t = 0; t < 24; t++) xF[(size_t)t*1048576 + tid] = xv[t];
}

__global__ void conv_lap1_k(const float* __restrict__ sup, u16* __restrict__ lh, u16* __restrict__ ll)
{
    const int i = blockIdx.x*256 + threadIdx.x;     // 262144; T1 row-major == sup
    const float v = sup[i];
    const u16 h = f2bf(v);
    lh[i] = h; ll[i] = f2bf(v - bf2f(h));
}

__global__ void lap2_k(const float* __restrict__ sup, u16* __restrict__ l2h, u16* __restrict__ l2l)
{
    __shared__ float As[16][17], Bs[16][17];
    const int tx = threadIdx.x & 15, ty = threadIdx.x >> 4;
    const int i0 = blockIdx.y*16, j0 = blockIdx.x*16;
    float acc = 0.f;
    for (int kt = 0; kt < 32; kt++){
        As[ty][tx] = sup[(i0 + ty)*512 + kt*16 + tx];
        Bs[ty][tx] = sup[(kt*16 + ty)*512 + j0 + tx];
        __syncthreads();
#pragma unroll
        for (int k = 0; k < 16; k++) acc = fmaf(As[ty][k], Bs[k][tx], acc);
        __syncthreads();
    }
    const int i = i0 + ty, j = j0 + tx;
    const float v = 2.f*acc - ((i == j) ? 1.f : 0.f);      // T2 = 2*sup@sup - I (row-major)
    const u16 h = f2bf(v);
    l2h[i*512 + j] = h; l2l[i*512 + j] = f2bf(v - bf2f(h));
}

__global__ void conv_w_k(const float* __restrict__ W, u16* __restrict__ wh, u16* __restrict__ wl)
{
    const int idx = blockIdx.x*256 + threadIdx.x;   // 256*320
    const int m = idx / 320, c = idx - m*320;
    float v = 0.f;
    if (c < 96)       v = W[m*288 + 3*c];            // k=0 (x:0..31, h:32..95)
    else if (c < 192) v = W[m*288 + 3*(c - 96) + 1]; // k=1
    else if (c < 288) v = W[m*288 + 3*(c - 192) + 2];// k=2
    const u16 h = f2bf(v);
    wh[idx] = h; wl[idx] = f2bf(v - bf2f(h));
}

// ===================== per-step elementwise =====================
template<int LEAN>
__global__ void init_k(float* __restrict__ cT,
                       u16* __restrict__ tAh, u16* __restrict__ tAl,
                       u16* __restrict__ gTh, u16* __restrict__ gTl,
                       const float* __restrict__ xsrc)
{
    const int idx = blockIdx.x*256 + threadIdx.x;   // 131072 = (b, q4, n)
    const int n = idx & 511;
    const int q4 = (idx >> 9) & 3;
    const int b = idx >> 11;
    const size_t row = (size_t)b*512 + n;
    float* cb = cT + row*64;
    u16* gh = gTh + row*320;
    u16* gl = gTl + row*320;
    const float4 z4f = make_float4(0.f, 0.f, 0.f, 0.f);
    const ushort4 z4 = make_ushort4(0, 0, 0, 0);
#pragma unroll
    for (int j = 0; j < 4; j++){
        *(float4*)&cb[q4*16 + j*4] = z4f;
        *(ushort4*)&gh[32 + q4*16 + j*4] = z4;
        *(ushort4*)&gl[32 + q4*16 + j*4] = z4;
    }
#pragma unroll
    for (int u = 0; u < 16; u++){
        tAh[((size_t)b*96 + 32 + q4*16 + u)*512 + n] = 0;
        tAl[((size_t)b*96 + 32 + q4*16 + u)*512 + n] = 0;
    }
    *(ushort4*)&gh[288 + q4*8]     = z4;  *(ushort4*)&gl[288 + q4*8]     = z4;
    *(ushort4*)&gh[288 + q4*8 + 4] = z4;  *(ushort4*)&gl[288 + q4*8 + 4] = z4;
    // x slots for t=0
#pragma unroll
    for (int cc = 0; cc < 2; cc++){
        const int c0 = q4*8 + cc*4;
        float xv[4];
#pragma unroll
        for (int r = 0; r < 4; r++){
            const int c = c0 + r;
            if constexpr (LEAN) xv[r] = xsrc[(((size_t)b*32 + c)*512 + n)*24 + 0];
            else                xv[r] = xsrc[((size_t)b*32 + c)*512 + n];
        }
        u16 xh[4], xl[4];
#pragma unroll
        for (int r = 0; r < 4; r++){ xh[r] = f2bf(xv[r]); xl[r] = f2bf(xv[r] - bf2f(xh[r])); }
        *(ushort4*)&gh[c0] = make_ushort4(xh[0], xh[1], xh[2], xh[3]);
        *(ushort4*)&gl[c0] = make_ushort4(xl[0], xl[1], xl[2], xl[3]);
#pragma unroll
        for (int r = 0; r < 4; r++){
            tAh[((size_t)b*96 + c0 + r)*512 + n] = xh[r];
            tAl[((size_t)b*96 + c0 + r)*512 + n] = xl[r];
        }
    }
}

template<int LEAN>
__global__ void gates_k(const float* __restrict__ feaT, float* __restrict__ cT,
                        u16* __restrict__ tAh, u16* __restrict__ tAl,
                        u16* __restrict__ gTh, u16* __restrict__ gTl,
                        const float* __restrict__ xsrc, float* __restrict__ odst, int t)
{
    const int idx = blockIdx.x*256 + threadIdx.x;   // 131072 = (b, q4, n)
    const int n = idx & 511;
    const int q4 = (idx >> 9) & 3;
    const int b = idx >> 11;
    const size_t row = (size_t)b*512 + n;
    const float* fb = feaT + row*256;
    float* cb = cT + row*64;
    u16* gh = gTh + row*320;
    u16* gl = gTl + row*320;

#pragma unroll
    for (int uc = 0; uc < 4; uc++){
        const int u0 = q4*16 + uc*4;
        const float4 iv = *(const float4*)&fb[u0];
        const float4 jv = *(const float4*)&fb[64 + u0];
        const float4 fv = *(const float4*)&fb[128 + u0];
        const float4 ov = *(const float4*)&fb[192 + u0];
        const float4 cv = *(const float4*)&cb[u0];
        float nc[4], nh[4];
        nc[0] = cv.x*sigf(fv.x) + sigf(iv.x)*tanhfast(jv.x);
        nc[1] = cv.y*sigf(fv.y) + sigf(iv.y)*tanhfast(jv.y);
        nc[2] = cv.z*sigf(fv.z) + sigf(iv.z)*tanhfast(jv.z);
        nc[3] = cv.w*sigf(fv.w) + sigf(iv.w)*tanhfast(jv.w);
        nh[0] = tanhfast(nc[0])*sigf(ov.x);
        nh[1] = tanhfast(nc[1])*sigf(ov.y);
        nh[2] = tanhfast(nc[2])*sigf(ov.z);
        nh[3] = tanhfast(nc[3])*sigf(ov.w);
        *(float4*)&cb[u0] = make_float4(nc[0], nc[1], nc[2], nc[3]);
        u16 hh[4], hl[4];
#pragma unroll
        for (int r = 0; r < 4; r++){ hh[r] = f2bf(nh[r]); hl[r] = f2bf(nh[r] - bf2f(hh[r])); }
        *(ushort4*)&gh[32 + u0] = make_ushort4(hh[0], hh[1], hh[2], hh[3]);
        *(ushort4*)&gl[32 + u0] = make_ushort4(hl[0], hl[1], hl[2], hl[3]);
#pragma unroll
        for (int r = 0; r < 4; r++){
            const int u = u0 + r;
            tAh[((size_t)b*96 + 32 + u)*512 + n] = hh[r];
            tAl[((size_t)b*96 + 32 + u)*512 + n] = hl[r];
            if constexpr (LEAN) odst[(((size_t)(b*64 + u))*512 + n)*24 + t] = nh[r];
            else                odst[((size_t)((t*64 + b)*64 + u))*512 + n] = nh[r];
        }
    }
    if (t < 23){
#pragma unroll
        for (int cc = 0; cc < 2; cc++){
            const int c0 = q4*8 + cc*4;
            float xv[4];
#pragma unroll
            for (int r = 0; r < 4; r++){
                const int c = c0 + r;
                if constexpr (LEAN) xv[r] = xsrc[(((size_t)b*32 + c)*512 + n)*24 + (t + 1)];
                else                xv[r] = xsrc[(size_t)(t + 1)*1048576 + ((size_t)b*32 + c)*512 + n];
            }
            u16 xh[4], xl[4];
#pragma unroll
            for (int r = 0; r < 4; r++){ xh[r] = f2bf(xv[r]); xl[r] = f2bf(xv[r] - bf2f(xh[r])); }
            *(ushort4*)&gh[c0] = make_ushort4(xh[0], xh[1], xh[2], xh[3]);
            *(ushort4*)&gl[c0] = make_ushort4(xl[0], xl[1], xl[2], xl[3]);
#pragma unroll
            for (int r = 0; r < 4; r++){
                tAh[((size_t)b*96 + c0 + r)*512 + n] = xh[r];
                tAl[((size_t)b*96 + c0 + r)*512 + n] = xl[r];
            }
        }
    }
}

__global__ void write_out_k(const float* __restrict__ hseq, float* __restrict__ out)
{
    __shared__ float tile[24][513];
    const int bu = blockIdx.x;                      // (b,u)
    const int tid = threadIdx.x;
    for (int i = tid; i < 24*512; i += 256){
        const int t = i >> 9, q = i & 511;
        tile[t][q] = hseq[(size_t)t*2097152 + (size_t)bu*512 + q];
    }
    __syncthreads();
    float* ob = out + (size_t)bu*(512*24);
    for (int i = tid; i < 512*24; i += 256){
        const int q = i / 24;
        const int t = i - q*24;
        ob[i] = tile[t][q];
    }
}

// ===================== launcher =====================
extern "C" void kernel_launch(void* const* d_in, const int* in_sizes, int n_in,
                              void* d_out, int out_size, void* d_ws, size_t ws_size,
                              hipStream_t stream)
{
    const float* x    = (const float*)d_in[0];  // [64,32,512,24]
    const float* sup  = (const float*)d_in[1];  // [512,512]
    const float* W    = (const float*)d_in[2];  // [256,288]
    const float* bias = (const float*)d_in[3];  // [256]
    float* out = (float*)d_out;                 // [64,64,512,24]

    char* p = (char*)d_ws;
    auto take = [&](size_t bytes) -> char* {
        char* r = p; p += (bytes + 255) & ~(size_t)255; return r;
    };
    u16*   lapTh = (u16*)take((size_t)2*262144*2);       // [z][512][512] T1,T2 row-major (hi)
    u16*   lapTl = (u16*)take((size_t)2*262144*2);
    u16*   Wph   = (u16*)take((size_t)256*320*2);
    u16*   Wpl   = (u16*)take((size_t)256*320*2);
    u16*   tAh   = (u16*)take((size_t)64*96*512*2);      // temA rows: [b][c(96)][n]
    u16*   tAl   = (u16*)take((size_t)64*96*512*2);
    u16*   gTh   = (u16*)take((size_t)64*512*320*2);     // [b][n][320] = GEMM2 B^T
    u16*   gTl   = (u16*)take((size_t)64*512*320*2);
    float* feaT  = (float*)take((size_t)64*512*256*4);   // [b][n][256]
    float* cT    = (float*)take((size_t)64*512*64*4);    // [b][n][64]
    const size_t fixed_bytes = (size_t)(p - (char*)d_ws);
    const size_t xF_bytes   = (size_t)24*1048576*4;
    const size_t hseq_bytes = (size_t)24*2097152*4;
    const int full = (ws_size >= fixed_bytes + xF_bytes + hseq_bytes + 1024) ? 1 : 0;
    float* xF   = (float*)take(xF_bytes);                // [t][b][c][n] (FULL only)
    float* hseq = (float*)take(hseq_bytes);              // [t][b][u][n] (FULL only)

    if (full) transpose_x_k<<<4096, 256, 0, stream>>>(x, xF);
    conv_lap1_k<<<1024, 256, 0, stream>>>(sup, lapTh, lapTl);
    lap2_k<<<dim3(32, 32), 256, 0, stream>>>(sup, lapTh + 262144, lapTl + 262144);
    conv_w_k<<<320, 256, 0, stream>>>(W, Wph, Wpl);
    if (full) init_k<0><<<512, 256, 0, stream>>>(cT, tAh, tAl, gTh, gTl, xF);
    else      init_k<1><<<512, 256, 0, stream>>>(cT, tAh, tAl, gTh, gTl, x);

    for (int t = 0; t < T_; t++){
        // GEMM1 (spatial): C[(b,c)][q] = tem @ T_z^T ; M=6144(BM=96/b), N=512, K=512, z=2
        mfma_gemm<3, 4, 512, 512, 8, 1><<<dim3(4, 64, 2), 256, 0, stream>>>(
            tAh, tAl, lapTh, lapTl, 262144, gTh, gTl, nullptr, nullptr);
        // GEMM2 (pointwise conv): feaT = W_perm @ gT^T + bias ; M=256, N=512, K=320, z=b
        mfma_gemm<4, 4, 320, 320, 5, 2><<<dim3(4, 2, 64), 256, 0, stream>>>(
            Wph, Wpl, gTh, gTl, 163840, nullptr, nullptr, feaT, bias);
        if (full) gates_k<0><<<512, 256, 0, stream>>>(feaT, cT, tAh, tAl, gTh, gTl, xF, hseq, t);
        else      gates_k<1><<<512, 256, 0, stream>>>(feaT, cT, tAh, tAl, gTh, gTl, x, out, t);
    }
    if (full) write_out_k<<<4096, 256, 0, stream>>>(hseq, out);
}

// Round 7
// 1781.492 us; speedup vs baseline: 2.6858x; 1.6565x over previous
//
#include <hip/hip_runtime.h>
#include <math.h>

#define B_    64
#define N_    512
#define T_    24

typedef unsigned short u16;
using f32x4  = __attribute__((ext_vector_type(4))) float;
using bf16x8 = __attribute__((ext_vector_type(8))) short;

__device__ __forceinline__ u16 f2bf(float f){
    unsigned u = __float_as_uint(f);
    u += 0x7fffu + ((u >> 16) & 1u);          // RTN-even
    return (u16)(u >> 16);
}
__device__ __forceinline__ float bf2f(u16 s){
    return __uint_as_float(((unsigned)s) << 16);
}
__device__ __forceinline__ void glds16(const u16* gp, u16* lp){
    __builtin_amdgcn_global_load_lds(
        (const __attribute__((address_space(1))) unsigned int*)gp,
        (__attribute__((address_space(3))) unsigned int*)lp, 16, 0, 0);
}
__device__ __forceinline__ float sigf(float v){ return 1.f / (1.f + __expf(-v)); }
__device__ __forceinline__ float tanhfast(float v){ return 2.f / (1.f + __expf(-2.f*v)) - 1.f; }

// ===================== GEMM1: split-bf16 MFMA (unchanged from r2) =====================
template<int MT, int NT, int AROW, int BROW, int NKIT, int EPI>
__global__ __launch_bounds__(256, 2)
void mfma_gemm(const u16* __restrict__ Agh, const u16* __restrict__ Agl,
               const u16* __restrict__ Bgh, const u16* __restrict__ Bgl,
               int bz,
               u16* __restrict__ gTh, u16* __restrict__ gTl,
               float* __restrict__ feaT, const float* __restrict__ bias)
{
    constexpr int BM = MT*32, BN = NT*32;
    constexpr int NIA = BM/8, NIB = BN/8;
    __shared__ __attribute__((aligned(16))) u16 Ah[BM*64];
    __shared__ __attribute__((aligned(16))) u16 Al[BM*64];
    __shared__ __attribute__((aligned(16))) u16 Bh[BN*64];
    __shared__ __attribute__((aligned(16))) u16 Bl[BN*64];

    const int tid  = threadIdx.x;
    const int lane = tid & 63, wave = tid >> 6;
    const int r16  = lane & 15, g = lane >> 4;
    const int wm = wave >> 1, wn = wave & 1;
    const int wtm0 = wm * (MT*16), wtn0 = wn * (NT*16);
    const int M0 = blockIdx.y * BM, N0 = blockIdx.x * BN;
    const int z  = blockIdx.z;

    unsigned offA[NIA/4], offB[NIB/4];
#pragma unroll
    for (int ii = 0; ii < NIA/4; ii++){
        int c = (wave + ii*4)*64 + lane;
        int m = c >> 3, gl = c & 7, gs = gl ^ (m & 7);
        offA[ii] = (unsigned)((M0 + m)*AROW + gs*8);
    }
#pragma unroll
    for (int ii = 0; ii < NIB/4; ii++){
        int c = (wave + ii*4)*64 + lane;
        int m = c >> 3, gl = c & 7, gs = gl ^ (m & 7);
        offB[ii] = (unsigned)(z*bz + (N0 + m)*BROW + gs*8);
    }

    f32x4 acc[MT][NT];
#pragma unroll
    for (int i = 0; i < MT; i++)
#pragma unroll
        for (int j = 0; j < NT; j++) acc[i][j] = (f32x4){0.f, 0.f, 0.f, 0.f};

#pragma unroll 1
    for (int kt = 0; kt < NKIT; kt++){
        const unsigned ko = kt * 64u;
#pragma unroll
        for (int ii = 0; ii < NIA/4; ii++){
            glds16(Agh + offA[ii] + ko, &Ah[(wave + ii*4)*512]);
            glds16(Agl + offA[ii] + ko, &Al[(wave + ii*4)*512]);
        }
#pragma unroll
        for (int ii = 0; ii < NIB/4; ii++){
            glds16(Bgh + offB[ii] + ko, &Bh[(wave + ii*4)*512]);
            glds16(Bgl + offB[ii] + ko, &Bl[(wave + ii*4)*512]);
        }
        __syncthreads();
#pragma unroll
        for (int s = 0; s < 2; s++){
            bf16x8 fah[MT], fal[MT], fbh[NT], fbl[NT];
#pragma unroll
            for (int im = 0; im < MT; im++){
                const int row = wtm0 + im*16 + r16;
                const int e = row*64 + ((((s<<2)|g) ^ (row & 7)))*8;
                fah[im] = *(const bf16x8*)&Ah[e];
                fal[im] = *(const bf16x8*)&Al[e];
            }
#pragma unroll
            for (int in = 0; in < NT; in++){
                const int row = wtn0 + in*16 + r16;
                const int e = row*64 + ((((s<<2)|g) ^ (row & 7)))*8;
                fbh[in] = *(const bf16x8*)&Bh[e];
                fbl[in] = *(const bf16x8*)&Bl[e];
            }
#pragma unroll
            for (int im = 0; im < MT; im++)
#pragma unroll
                for (int in = 0; in < NT; in++){
                    acc[im][in] = __builtin_amdgcn_mfma_f32_16x16x32_bf16(fah[im], fbh[in], acc[im][in], 0, 0, 0);
                    acc[im][in] = __builtin_amdgcn_mfma_f32_16x16x32_bf16(fah[im], fbl[in], acc[im][in], 0, 0, 0);
                    acc[im][in] = __builtin_amdgcn_mfma_f32_16x16x32_bf16(fal[im], fbh[in], acc[im][in], 0, 0, 0);
                }
        }
        __syncthreads();
    }

#pragma unroll
    for (int im = 0; im < MT; im++){
        const int mr = M0 + wtm0 + im*16 + g*4;
#pragma unroll
        for (int in = 0; in < NT; in++){
            const int q = N0 + wtn0 + in*16 + r16;
            const f32x4 v = acc[im][in];
            if constexpr (EPI == 1){
                const int c = mr - M0;
                const size_t off = ((size_t)(blockIdx.y*512 + q))*320 + 96*(z + 1) + c;
                float vv[4] = {v.x, v.y, v.z, v.w};
                u16 hh[4], hl[4];
#pragma unroll
                for (int r = 0; r < 4; r++){ hh[r] = f2bf(vv[r]); hl[r] = f2bf(vv[r] - bf2f(hh[r])); }
                *(ushort4*)&gTh[off] = make_ushort4(hh[0], hh[1], hh[2], hh[3]);
                *(ushort4*)&gTl[off] = make_ushort4(hl[0], hl[1], hl[2], hl[3]);
            } else {
                const float4 bv = *(const float4*)&bias[mr];
                float4 o = make_float4(v.x + bv.x, v.y + bv.y, v.z + bv.z, v.w + bv.w);
                *(float4*)&feaT[((size_t)(z*512 + q))*256 + mr] = o;
            }
        }
    }
}

// ===================== GEMM2 + gates FUSED =====================
// feaT round-trip eliminated: fea staged in LDS (aliased over A-tile), gates applied in-epilogue.
// BM=256 (all 4 gate quadrants), BN=64, K=320, 512 threads (8 waves = 4M x 2N).
template<int LEAN>
__global__ __launch_bounds__(512, 2)
void gemm2_fused(const u16* __restrict__ Wph, const u16* __restrict__ Wpl,
                 u16* __restrict__ gTh, u16* __restrict__ gTl,
                 float* __restrict__ cT,
                 u16* __restrict__ tAh, u16* __restrict__ tAl,
                 const float* __restrict__ bias,
                 const float* __restrict__ xsrc, float* __restrict__ odst, int t)
{
    __shared__ __attribute__((aligned(16))) u16 smem[40960];   // 80 KB
    u16* Ah = smem;              // 16384 u16 (32 KB): W hi tile 256x64
    u16* Al = smem + 16384;      // 32 KB: W lo
    u16* Bh = smem + 32768;      // 8 KB: gT hi tile 64x64
    u16* Bl = smem + 36864;      // 8 KB
    float* fea = (float*)smem;   // 64 KB [256][64] — aliases Ah/Al (dead after K-loop)

    const int tid  = threadIdx.x;
    const int lane = tid & 63, wave = tid >> 6;
    const int r16  = lane & 15, g = lane >> 4;
    const int wm = wave >> 1, wn = wave & 1;     // 4 M-waves x 2 N-waves
    const int N0 = blockIdx.x * 64;
    const int b  = blockIdx.z;

    // staging offsets (source pre-swizzled: chunk gl reads gsrc = gl^(m&7))
    unsigned offA[4], offB;
#pragma unroll
    for (int ii = 0; ii < 4; ii++){
        int c = ii*512 + wave*64 + lane;
        int m = c >> 3, gl = c & 7, gs = gl ^ (m & 7);
        offA[ii] = (unsigned)(m*320 + gs*8);
    }
    {
        int c = wave*64 + lane;
        int m = c >> 3, gl = c & 7, gs = gl ^ (m & 7);
        offB = (unsigned)(b*163840 + (N0 + m)*320 + gs*8);
    }

    f32x4 acc[4][2];
#pragma unroll
    for (int i = 0; i < 4; i++)
#pragma unroll
        for (int j = 0; j < 2; j++) acc[i][j] = (f32x4){0.f, 0.f, 0.f, 0.f};

#pragma unroll 1
    for (int kt = 0; kt < 5; kt++){
        const unsigned ko = kt * 64u;
#pragma unroll
        for (int ii = 0; ii < 4; ii++){
            glds16(Wph + offA[ii] + ko, &Ah[(ii*512 + wave*64)*8]);
            glds16(Wpl + offA[ii] + ko, &Al[(ii*512 + wave*64)*8]);
        }
        glds16(gTh + offB + ko, &Bh[wave*512]);
        glds16(gTl + offB + ko, &Bl[wave*512]);
        __syncthreads();
#pragma unroll
        for (int s = 0; s < 2; s++){
            bf16x8 fah[4], fal[4], fbh[2], fbl[2];
#pragma unroll
            for (int im = 0; im < 4; im++){
                const int row = wm*64 + im*16 + r16;
                const int e = row*64 + ((((s<<2)|g) ^ (row & 7)))*8;
                fah[im] = *(const bf16x8*)&Ah[e];
                fal[im] = *(const bf16x8*)&Al[e];
            }
#pragma unroll
            for (int in = 0; in < 2; in++){
                const int row = wn*32 + in*16 + r16;
                const int e = row*64 + ((((s<<2)|g) ^ (row & 7)))*8;
                fbh[in] = *(const bf16x8*)&Bh[e];
                fbl[in] = *(const bf16x8*)&Bl[e];
            }
#pragma unroll
            for (int im = 0; im < 4; im++)
#pragma unroll
                for (int in = 0; in < 2; in++){
                    acc[im][in] = __builtin_amdgcn_mfma_f32_16x16x32_bf16(fah[im], fbh[in], acc[im][in], 0, 0, 0);
                    acc[im][in] = __builtin_amdgcn_mfma_f32_16x16x32_bf16(fah[im], fbl[in], acc[im][in], 0, 0, 0);
                    acc[im][in] = __builtin_amdgcn_mfma_f32_16x16x32_bf16(fal[im], fbh[in], acc[im][in], 0, 0, 0);
                }
        }
        __syncthreads();   // also guards the fea-over-A alias below on last iter
    }

    // stage fea (+bias) into LDS [m][n]
#pragma unroll
    for (int im = 0; im < 4; im++){
        const int m0 = wm*64 + im*16 + g*4;
        const float4 bv = *(const float4*)&bias[m0];
        const float bb[4] = {bv.x, bv.y, bv.z, bv.w};
#pragma unroll
        for (int in = 0; in < 2; in++){
            const int n = wn*32 + in*16 + r16;
            const f32x4 v = acc[im][in];
            fea[(m0 + 0)*64 + n] = v.x + bb[0];
            fea[(m0 + 1)*64 + n] = v.y + bb[1];
            fea[(m0 + 2)*64 + n] = v.z + bb[2];
            fea[(m0 + 3)*64 + n] = v.w + bb[3];
        }
    }
    __syncthreads();

    // gates: thread = (ug, n_loc); 8 u's per thread
    const int n_loc = tid & 63;
    const int ug    = tid >> 6;
    const int n_g   = N0 + n_loc;
    const size_t row = (size_t)b*512 + n_g;
    float* cb = cT + row*64;
    u16* gh = gTh + row*320;
    u16* gl = gTl + row*320;
    const int u0 = ug*8;

    float cold[8];
    *(float4*)&cold[0] = *(const float4*)&cb[u0];
    *(float4*)&cold[4] = *(const float4*)&cb[u0 + 4];
    float ncv[8], nhv[8];
    u16 hh[8], hl[8];
#pragma unroll
    for (int jj = 0; jj < 8; jj++){
        const int u = u0 + jj;
        const float iv = fea[u*64 + n_loc];
        const float jv = fea[(64 + u)*64 + n_loc];
        const float fv = fea[(128 + u)*64 + n_loc];
        const float ov = fea[(192 + u)*64 + n_loc];
        const float nc = cold[jj]*sigf(fv) + sigf(iv)*tanhfast(jv);
        const float nh = tanhfast(nc)*sigf(ov);
        ncv[jj] = nc; nhv[jj] = nh;
        hh[jj] = f2bf(nh); hl[jj] = f2bf(nh - bf2f(hh[jj]));
    }
    *(float4*)&cb[u0]     = *(const float4*)&ncv[0];
    *(float4*)&cb[u0 + 4] = *(const float4*)&ncv[4];
    *(ushort4*)&gh[32 + u0]     = make_ushort4(hh[0], hh[1], hh[2], hh[3]);
    *(ushort4*)&gh[32 + u0 + 4] = make_ushort4(hh[4], hh[5], hh[6], hh[7]);
    *(ushort4*)&gl[32 + u0]     = make_ushort4(hl[0], hl[1], hl[2], hl[3]);
    *(ushort4*)&gl[32 + u0 + 4] = make_ushort4(hl[4], hl[5], hl[6], hl[7]);
#pragma unroll
    for (int jj = 0; jj < 8; jj++){
        const int u = u0 + jj;
        tAh[((size_t)b*96 + 32 + u)*512 + n_g] = hh[jj];
        tAl[((size_t)b*96 + 32 + u)*512 + n_g] = hl[jj];
        if constexpr (LEAN) odst[(((size_t)b*64 + u)*512 + n_g)*24 + t] = nhv[jj];
        else                odst[(size_t)t*2097152 + ((size_t)b*64 + u)*512 + n_g] = nhv[jj];
    }

    // x(t+1) into k=0 slots
    if (t < 23){
#pragma unroll
        for (int jj = 0; jj < 4; jj++){
            const int c = ug*4 + jj;
            float xv;
            if constexpr (LEAN) xv = xsrc[(((size_t)b*32 + c)*512 + n_g)*24 + (t + 1)];
            else                xv = xsrc[(size_t)(t + 1)*1048576 + ((size_t)b*32 + c)*512 + n_g];
            const u16 xh = f2bf(xv), xl = f2bf(xv - bf2f(xh));
            gh[c] = xh; gl[c] = xl;
            tAh[((size_t)b*96 + c)*512 + n_g] = xh;
            tAl[((size_t)b*96 + c)*512 + n_g] = xl;
        }
    }
}

// ===================== setup kernels (unchanged) =====================
__global__ void transpose_x_k(const float* __restrict__ x, float* __restrict__ xF)
{
    const int tid = blockIdx.x*256 + threadIdx.x;
    float xv[24];
    const float4* xp = (const float4*)(x + (size_t)tid*24);
#pragma unroll
    for (int j = 0; j < 6; j++) *(float4*)&xv[j*4] = xp[j];
#pragma unroll
    for (int t = 0; t < 24; t++) xF[(size_t)t*1048576 + tid] = xv[t];
}

__global__ void conv_lap1_k(const float* __restrict__ sup, u16* __restrict__ lh, u16* __restrict__ ll)
{
    const int i = blockIdx.x*256 + threadIdx.x;
    const float v = sup[i];
    const u16 h = f2bf(v);
    lh[i] = h; ll[i] = f2bf(v - bf2f(h));
}

__global__ void lap2_k(const float* __restrict__ sup, u16* __restrict__ l2h, u16* __restrict__ l2l)
{
    __shared__ float As[16][17], Bs[16][17];
    const int tx = threadIdx.x & 15, ty = threadIdx.x >> 4;
    const int i0 = blockIdx.y*16, j0 = blockIdx.x*16;
    float acc = 0.f;
    for (int kt = 0; kt < 32; kt++){
        As[ty][tx] = sup[(i0 + ty)*512 + kt*16 + tx];
        Bs[ty][tx] = sup[(kt*16 + ty)*512 + j0 + tx];
        __syncthreads();
#pragma unroll
        for (int k = 0; k < 16; k++) acc = fmaf(As[ty][k], Bs[k][tx], acc);
        __syncthreads();
    }
    const int i = i0 + ty, j = j0 + tx;
    const float v = 2.f*acc - ((i == j) ? 1.f : 0.f);
    const u16 h = f2bf(v);
    l2h[i*512 + j] = h; l2l[i*512 + j] = f2bf(v - bf2f(h));
}

__global__ void conv_w_k(const float* __restrict__ W, u16* __restrict__ wh, u16* __restrict__ wl)
{
    const int idx = blockIdx.x*256 + threadIdx.x;
    const int m = idx / 320, c = idx - m*320;
    float v = 0.f;
    if (c < 96)       v = W[m*288 + 3*c];
    else if (c < 192) v = W[m*288 + 3*(c - 96) + 1];
    else if (c < 288) v = W[m*288 + 3*(c - 192) + 2];
    const u16 h = f2bf(v);
    wh[idx] = h; wl[idx] = f2bf(v - bf2f(h));
}

template<int LEAN>
__global__ void init_k(float* __restrict__ cT,
                       u16* __restrict__ tAh, u16* __restrict__ tAl,
                       u16* __restrict__ gTh, u16* __restrict__ gTl,
                       const float* __restrict__ xsrc)
{
    const int idx = blockIdx.x*256 + threadIdx.x;
    const int n = idx & 511;
    const int q4 = (idx >> 9) & 3;
    const int b = idx >> 11;
    const size_t row = (size_t)b*512 + n;
    float* cb = cT + row*64;
    u16* gh = gTh + row*320;
    u16* gl = gTl + row*320;
    const float4 z4f = make_float4(0.f, 0.f, 0.f, 0.f);
    const ushort4 z4 = make_ushort4(0, 0, 0, 0);
#pragma unroll
    for (int j = 0; j < 4; j++){
        *(float4*)&cb[q4*16 + j*4] = z4f;
        *(ushort4*)&gh[32 + q4*16 + j*4] = z4;
        *(ushort4*)&gl[32 + q4*16 + j*4] = z4;
    }
#pragma unroll
    for (int u = 0; u < 16; u++){
        tAh[((size_t)b*96 + 32 + q4*16 + u)*512 + n] = 0;
        tAl[((size_t)b*96 + 32 + q4*16 + u)*512 + n] = 0;
    }
    *(ushort4*)&gh[288 + q4*8]     = z4;  *(ushort4*)&gl[288 + q4*8]     = z4;
    *(ushort4*)&gh[288 + q4*8 + 4] = z4;  *(ushort4*)&gl[288 + q4*8 + 4] = z4;
#pragma unroll
    for (int cc = 0; cc < 2; cc++){
        const int c0 = q4*8 + cc*4;
        float xv[4];
#pragma unroll
        for (int r = 0; r < 4; r++){
            const int c = c0 + r;
            if constexpr (LEAN) xv[r] = xsrc[(((size_t)b*32 + c)*512 + n)*24 + 0];
            else                xv[r] = xsrc[((size_t)b*32 + c)*512 + n];
        }
        u16 xh[4], xl[4];
#pragma unroll
        for (int r = 0; r < 4; r++){ xh[r] = f2bf(xv[r]); xl[r] = f2bf(xv[r] - bf2f(xh[r])); }
        *(ushort4*)&gh[c0] = make_ushort4(xh[0], xh[1], xh[2], xh[3]);
        *(ushort4*)&gl[c0] = make_ushort4(xl[0], xl[1], xl[2], xl[3]);
#pragma unroll
        for (int r = 0; r < 4; r++){
            tAh[((size_t)b*96 + c0 + r)*512 + n] = xh[r];
            tAl[((size_t)b*96 + c0 + r)*512 + n] = xl[r];
        }
    }
}

__global__ void write_out_k(const float* __restrict__ hseq, float* __restrict__ out)
{
    __shared__ float tile[24][513];
    const int bu = blockIdx.x;
    const int tid = threadIdx.x;
    for (int i = tid; i < 24*512; i += 256){
        const int t = i >> 9, q = i & 511;
        tile[t][q] = hseq[(size_t)t*2097152 + (size_t)bu*512 + q];
    }
    __syncthreads();
    float* ob = out + (size_t)bu*(512*24);
    for (int i = tid; i < 512*24; i += 256){
        const int q = i / 24;
        const int t = i - q*24;
        ob[i] = tile[t][q];
    }
}

// ===================== launcher =====================
extern "C" void kernel_launch(void* const* d_in, const int* in_sizes, int n_in,
                              void* d_out, int out_size, void* d_ws, size_t ws_size,
                              hipStream_t stream)
{
    const float* x    = (const float*)d_in[0];
    const float* sup  = (const float*)d_in[1];
    const float* W    = (const float*)d_in[2];
    const float* bias = (const float*)d_in[3];
    float* out = (float*)d_out;

    char* p = (char*)d_ws;
    auto take = [&](size_t bytes) -> char* {
        char* r = p; p += (bytes + 255) & ~(size_t)255; return r;
    };
    u16*   lapTh = (u16*)take((size_t)2*262144*2);
    u16*   lapTl = (u16*)take((size_t)2*262144*2);
    u16*   Wph   = (u16*)take((size_t)256*320*2);
    u16*   Wpl   = (u16*)take((size_t)256*320*2);
    u16*   tAh   = (u16*)take((size_t)64*96*512*2);
    u16*   tAl   = (u16*)take((size_t)64*96*512*2);
    u16*   gTh   = (u16*)take((size_t)64*512*320*2);
    u16*   gTl   = (u16*)take((size_t)64*512*320*2);
    float* cT    = (float*)take((size_t)64*512*64*4);
    const size_t fixed_bytes = (size_t)(p - (char*)d_ws);
    const size_t xF_bytes   = (size_t)24*1048576*4;
    const size_t hseq_bytes = (size_t)24*2097152*4;
    const int full = (ws_size >= fixed_bytes + xF_bytes + hseq_bytes + 1024) ? 1 : 0;
    float* xF   = (float*)take(xF_bytes);
    float* hseq = (float*)take(hseq_bytes);

    if (full) transpose_x_k<<<4096, 256, 0, stream>>>(x, xF);
    conv_lap1_k<<<1024, 256, 0, stream>>>(sup, lapTh, lapTl);
    lap2_k<<<dim3(32, 32), 256, 0, stream>>>(sup, lapTh + 262144, lapTl + 262144);
    conv_w_k<<<320, 256, 0, stream>>>(W, Wph, Wpl);
    if (full) init_k<0><<<512, 256, 0, stream>>>(cT, tAh, tAl, gTh, gTl, xF);
    else      init_k<1><<<512, 256, 0, stream>>>(cT, tAh, tAl, gTh, gTl, x);

    for (int t = 0; t < T_; t++){
        // GEMM1 (spatial): M=6144 (96/b), N=512, K=512, z=2
        mfma_gemm<3, 4, 512, 512, 8, 1><<<dim3(4, 64, 2), 256, 0, stream>>>(
            tAh, tAl, lapTh, lapTl, 262144, gTh, gTl, nullptr, nullptr);
        // GEMM2 + gates fused: M=256, N=512 (64/block), K=320, z=b
        if (full) gemm2_fused<0><<<dim3(8, 1, 64), 512, 0, stream>>>(
            Wph, Wpl, gTh, gTl, cT, tAh, tAl, bias, xF, hseq, t);
        else      gemm2_fused<1><<<dim3(8, 1, 64), 512, 0, stream>>>(
            Wph, Wpl, gTh, gTl, cT, tAh, tAl, bias, x, out, t);
    }
    if (full) write_out_k<<<4096, 256, 0, stream>>>(hseq, out);
}